// Round 5
// baseline (262.009 us; speedup 1.0000x reference)
//
#include <hip/hip_runtime.h>

// Separable 5x5 Gaussian blur, sigma=1.1, BORDER_REFLECT_101, NHWC fp32.
// Shape: (64, 384, 512, 3). Row = 512*3 = 1536 floats = 384 float4.
// NOTE: horizontal taps are stride-3 in floats (per-channel, C=3).
//
// Quad-tile pipelined, barrier-free, wave-private double-buffered LDS.
// One block per (batch, 16-row quad tile); 512 threads = 8 waves. Wave
// w owns 48 output float4 columns (q0=48w) and loads a 64-column window
// (cols q0-2..q0+61, halo included). Register sliding window keeps the
// load pipeline 2 TILES DEEP: prologue pins rows h0-2..h0+9 (12 loads),
// and iterations 0/1 issue tile t+2's 4 rows before computing tile t
// (sched_barrier(0) forbids the compiler sinking them). Vertical sums
// go to the wave's PRIVATE LDS strip, double-buffered by tile parity so
// tile t's ds_writes never wait on tile t-1's hpass ds_reads (no WAR
// lgkmcnt stall). reflect-101 horizontal pads fixed from the wave's own
// data; horizontal pass (lanes 0..47) reads same-wave LDS only -> NO
// __syncthreads anywhere. 20 loads / 16 output rows = 1.25x demand.
// Nontemporal stores keep input L3-resident; XCD swizzle gives each XCD
// contiguous tiles.

#define BN 64
#define HN 384
#define WN 512
#define CN 3
#define ROWF (WN * CN)              // 1536 floats per row
#define ROWQ (ROWF / 4)             // 384 float4 per row
#define TH 4                        // rows per tile
#define NTILE 4                     // tiles per block
#define DTH (TH * NTILE)            // 16 rows per block
#define NDT (HN / DTH)              // 24 quad-tiles per image
#define NTHR 512                    // 8 waves per block
#define NBLK (BN * NDT)             // 1536 blocks

// Gaussian taps for ksize=5, sigma=1.1 (precomputed, normalized):
#define CW0 0.07076630f
#define CW1 0.24446040f
#define CW2 0.36954650f

// Native clang vector type: __builtin_nontemporal_store requires it.
typedef float vfloat4 __attribute__((ext_vector_type(4)));

__device__ __forceinline__ void vpass(const float4* win, float* vw, int l) {
#pragma unroll
    for (int r = 0; r < TH; ++r) {
        float4 a;
        a.x = CW0 * (win[r].x + win[r + 4].x) +
              CW1 * (win[r + 1].x + win[r + 3].x) + CW2 * win[r + 2].x;
        a.y = CW0 * (win[r].y + win[r + 4].y) +
              CW1 * (win[r + 1].y + win[r + 3].y) + CW2 * win[r + 2].y;
        a.z = CW0 * (win[r].z + win[r + 4].z) +
              CW1 * (win[r + 1].z + win[r + 3].z) + CW2 * win[r + 2].z;
        a.w = CW0 * (win[r].w + win[r + 4].w) +
              CW1 * (win[r + 1].w + win[r + 3].w) + CW2 * win[r + 2].w;
        ((float4*)(vw + r * 256))[l] = a;
    }
}

__device__ __forceinline__ void pads(float* vw, int q0, int l) {
    // reflect101 horizontal pads, window-float indexed (wf = g - 4*q0 + 8):
    //   wave 0: g=-6..-1 <- {6,7,8,3,4,5}          => wf 2..7 <- {14,15,16,11,12,13}
    //   wave 7: g=1536..1541 <- {1530..32,1527..29} => wf 200..205 <- {194,195,196,191,192,193}
    if (q0 == 0 && l < TH * 6) {
        int r = l / 6, p = l - 6 * r;
        float* vr = vw + r * 256;
        vr[2 + p] = vr[p < 3 ? 14 + p : 8 + p];
    } else if (q0 == 336 && l < TH * 6) {
        int r = l / 6, p = l - 6 * r;
        float* vr = vw + r * 256;
        vr[200 + p] = vr[p < 3 ? 194 + p : 188 + p];
    }
}

__device__ __forceinline__ void hpass(const float* vw, float* ob, int q0, int l) {
    if (l < 48) {
#pragma unroll
        for (int r = 0; r < TH; ++r) {
            const float* vr = vw + r * 256;
            float wnd[20];                 // window floats 4l .. 4l+19
#pragma unroll
            for (int k = 0; k < 5; ++k) {
                float4 t = ((const float4*)vr)[l + k];
                wnd[4 * k + 0] = t.x;
                wnd[4 * k + 1] = t.y;
                wnd[4 * k + 2] = t.z;
                wnd[4 * k + 3] = t.w;
            }
            vfloat4 res;
#pragma unroll
            for (int j = 0; j < 4; ++j) {   // stride-3 taps: per-channel
                res[j] =
                    CW0 * (wnd[j + 2] + wnd[j + 14]) +
                    CW1 * (wnd[j + 5] + wnd[j + 11]) +
                    CW2 * wnd[j + 8];
            }
            __builtin_nontemporal_store(res,
                &((vfloat4*)ob)[r * ROWQ + q0 + l]);
        }
    }
}

__global__ __launch_bounds__(NTHR, 4) void gauss_blur_fused(
        const float* __restrict__ x, float* __restrict__ out) {
    // 8 waves * 2 buffers * 4 rows * 256 floats = 65536 B
    __shared__ float v[8 * 2 * TH * 256];

    // XCD-contiguous tile swizzle: XCD k (blockIdx%8) gets quad-tiles
    // [k*192, (k+1)*192) in linear order.
    const int bid  = blockIdx.x;
    const int tile = (bid & 7) * (NBLK >> 3) + (bid >> 3);
    const int b    = tile / NDT;
    const int h0   = (tile - b * NDT) * DTH;
    const float* __restrict__ xb = x + (size_t)b * HN * ROWF;
    float* __restrict__ ob = out + ((size_t)b * HN + h0) * ROWF;

    const int wid = threadIdx.x >> 6;    // wave 0..7
    const int l   = threadIdx.x & 63;    // lane
    const int q0  = wid * 48;            // first output float4 column
    int c = q0 - 2 + l;                  // this lane's window column
    c = c < 0 ? 0 : (c > ROWQ - 1 ? ROWQ - 1 : c);   // clamp (pads fix edges)

    // ---- prologue: pin 12 row-loads (tile0 window + tile1's new rows)
    float4 win[8], nxt[TH];
#pragma unroll
    for (int i = 0; i < 8; ++i) {
        int hs = h0 + i - 2;
        hs = hs < 0 ? -hs : hs;                 // reflect101 low (uniform)
        win[i] = ((const float4*)(xb + (size_t)hs * ROWF))[c];
    }
#pragma unroll
    for (int i = 0; i < TH; ++i) {
        int hs = h0 + 6 + i;                    // rows h0+6..h0+9, always valid
        nxt[i] = ((const float4*)(xb + (size_t)hs * ROWF))[c];
    }
    __builtin_amdgcn_sched_barrier(0);   // forbid sinking the loads

    float* const vb = v + wid * (2 * TH * 256);   // wave's strip pair

#pragma unroll
    for (int t = 0; t < NTILE; ++t) {
        // issue tile t+2's 4 row-loads before computing tile t
        float4 nn[TH];
        if (t < NTILE - 2) {
            const int rb = h0 + 4 * t + 10;
#pragma unroll
            for (int i = 0; i < TH; ++i) {
                int hs = rb + i;
                hs = hs >= HN ? 2 * HN - 2 - hs : hs;   // reflect101 high
                nn[i] = ((const float4*)(xb + (size_t)hs * ROWF))[c];
            }
            __builtin_amdgcn_sched_barrier(0);
        }

        float* const vw = vb + (t & 1) * (TH * 256);   // A/B by parity
        vpass(win, vw, l);
        pads(vw, q0, l);
        hpass(vw, ob + t * TH * ROWF, q0, l);

        // slide the register window down one tile
        if (t < NTILE - 1) {
#pragma unroll
            for (int i = 0; i < TH; ++i) win[i] = win[i + 4];
#pragma unroll
            for (int i = 0; i < TH; ++i) win[TH + i] = nxt[i];
        }
        if (t < NTILE - 2) {
#pragma unroll
            for (int i = 0; i < TH; ++i) nxt[i] = nn[i];
        }
    }
}

extern "C" void kernel_launch(void* const* d_in, const int* in_sizes, int n_in,
                              void* d_out, int out_size, void* d_ws, size_t ws_size,
                              hipStream_t stream) {
    const float* x = (const float*)d_in[0];
    float* out = (float*)d_out;
    gauss_blur_fused<<<dim3(NBLK), dim3(NTHR), 0, stream>>>(x, out);
}